// Round 1
// baseline (360.683 us; speedup 1.0000x reference)
//
#include <hip/hip_runtime.h>
#include <hip/hip_bf16.h>

#define DIM 384
#define SEQ 3136   // 56*56
#define NBATCH 8

typedef __attribute__((ext_vector_type(8))) short short8;  // 8 x bf16 (4 VGPRs)
typedef __attribute__((ext_vector_type(4))) float fx4;
typedef __attribute__((ext_vector_type(4))) int i4;
typedef __hip_bfloat16 bf16;

#define MFMA(a,b,c) __builtin_amdgcn_mfma_f32_16x16x32_bf16(a,b,c,0,0,0)

// -------- x[b][c][n] f32 -> kb[b][n][c] bf16 (transpose + convert) --------
__global__ __launch_bounds__(256) void ktrans(const float* __restrict__ x,
                                              bf16* __restrict__ kb) {
  __shared__ float t[64][65];
  int b = blockIdx.z;
  int n0 = blockIdx.x * 64, c0 = blockIdx.y * 64;
  int tid = threadIdx.x;
  {
    int nl = tid & 63, cl = tid >> 6;
    const float* xp = x + ((size_t)b * DIM + c0) * SEQ + n0;
    #pragma unroll
    for (int p = 0; p < 16; ++p) {
      int c = cl * 16 + p;
      t[c][nl] = xp[(size_t)c * SEQ + nl];
    }
  }
  __syncthreads();
  {
    int cc = tid & 63, nr = tid >> 6;
    bf16* kp = kb + ((size_t)b * SEQ + n0) * DIM + c0;
    #pragma unroll
    for (int p = 0; p < 16; ++p) {
      int n = nr * 16 + p;
      kp[(size_t)n * DIM + cc] = __float2bfloat16(t[cc][n]);
    }
  }
}

// -------- weights f32 -> bf16 --------
__global__ __launch_bounds__(256) void kwconv(const float* __restrict__ w1,
                                              const float* __restrict__ w2,
                                              bf16* __restrict__ w1b,
                                              bf16* __restrict__ w2b) {
  int i = blockIdx.x * 256 + threadIdx.x;   // grid covers DIM*DIM exactly
  w1b[i] = __float2bfloat16(w1[i]);
  w2b[i] = __float2bfloat16(w2[i]);
}

// -------- out[r][c] = sum_k A[r][k] * Bt[c][k]   (both K-contiguous, K=384) --------
__global__ __launch_bounds__(256, 1) void kgemm(const bf16* __restrict__ A, long long Abs,
                                                const bf16* __restrict__ Bt, long long Bbs,
                                                bf16* __restrict__ out, long long Obs, int ldo) {
  __shared__ __align__(16) bf16 At[64][DIM + 8];
  __shared__ __align__(16) bf16 Bs[64][DIM + 8];
  int b = blockIdx.z;
  int tid = threadIdx.x;
  const bf16* Ab = A + (size_t)b * Abs + (size_t)blockIdx.x * 64 * DIM;
  const bf16* Bb = Bt + (size_t)b * Bbs + (size_t)blockIdx.y * 64 * DIM;
  {
    int row = tid >> 2, cb = (tid & 3) * 96;
    const i4* ga = (const i4*)(Ab + (size_t)row * DIM + cb);
    const i4* gb = (const i4*)(Bb + (size_t)row * DIM + cb);
    i4* la = (i4*)(&At[row][cb]);
    i4* lb = (i4*)(&Bs[row][cb]);
    #pragma unroll
    for (int p = 0; p < 12; ++p) { la[p] = ga[p]; lb[p] = gb[p]; }
  }
  __syncthreads();
  int wave = tid >> 6, lane = tid & 63;
  int r = lane & 15, kq = lane >> 4;
  fx4 zero = {0.f, 0.f, 0.f, 0.f};
  fx4 acc[4];
  #pragma unroll
  for (int i = 0; i < 4; ++i) acc[i] = zero;
  #pragma unroll
  for (int ks = 0; ks < 12; ++ks) {
    short8 af = *(const short8*)(&At[wave * 16 + r][ks * 32 + kq * 8]);
    #pragma unroll
    for (int ct = 0; ct < 4; ++ct) {
      short8 bfr = *(const short8*)(&Bs[ct * 16 + r][ks * 32 + kq * 8]);
      acc[ct] = MFMA(af, bfr, acc[ct]);
    }
  }
  bf16* ob = out + (size_t)b * Obs
           + (size_t)(blockIdx.x * 64 + wave * 16 + kq * 4) * ldo + blockIdx.y * 64;
  #pragma unroll
  for (int ct = 0; ct < 4; ++ct)
    #pragma unroll
    for (int rr = 0; rr < 4; ++rr)
      ob[(size_t)rr * ldo + ct * 16 + r] = __float2bfloat16(acc[ct][rr]);
}

// -------- fused attention: S = Q*K^T (no-max softmax), O = P*V / rowsum --------
// grid (8, 49): blockIdx.x = batch (-> XCD via %8), blockIdx.y = n-tile (64 rows).
// m-tile 32, 98 iters. K AND V staged in LDS via coalesced loads (no divergent
// global gathers). 3-barrier software pipeline per iter:
//   QK -> SM -> bB -> [issue next K/V global loads to regs] -> PV -> bA ->
//   [LDS writes] -> bC
// so the compiler's vmcnt(0) drain at bA lands after PV has hidden the load
// latency. LDS 57.6KB -> 2 blocks/CU. Strides chosen for balanced banks:
//   Kl stride 392 (as before), Vl/Pl stride 36 elems (b128 reads: 8 acc/bank
//   minimum; b16 P-stores: 32 distinct banks).
__global__ __launch_bounds__(256, 2) void kattn(const bf16* __restrict__ Qb,
                                                const bf16* __restrict__ Kb,
                                                const bf16* __restrict__ Vt,
                                                float* __restrict__ out) {
  __shared__ __align__(16) bf16 Kl[32][DIM + 8];   // 25,088 B  (m rows x c)
  __shared__ __align__(16) bf16 Vl[DIM][36];       // 27,648 B  (d rows x m)
  __shared__ __align__(16) bf16 Pl[4][16][36];     //  4,608 B
  __shared__ float rsum[64];

  int b = blockIdx.x;
  int n0 = blockIdx.y * 64;
  int tid = threadIdx.x;
  int wave = tid >> 6, lane = tid & 63;
  int r = lane & 15, kq = lane >> 4;

  // Q fragments for this wave's 16 rows, full K=384 (12 k-steps)
  short8 qf[12];
  {
    const bf16* qp = Qb + ((size_t)b * SEQ + n0 + wave * 16 + r) * DIM + kq * 8;
    #pragma unroll
    for (int ks = 0; ks < 12; ++ks) qf[ks] = *(const short8*)(qp + ks * 32);
  }
  fx4 zero = {0.f, 0.f, 0.f, 0.f};
  fx4 acc[4][6];
  #pragma unroll
  for (int i = 0; i < 4; ++i)
    #pragma unroll
    for (int j = 0; j < 6; ++j) acc[i][j] = zero;
  float rs[4] = {0.f, 0.f, 0.f, 0.f};
  const float cexp = 0.07362223f;   // log2(e)/sqrt(384): exp(s*scale) = exp2(s*cexp)

  const bf16* kbase = Kb + (size_t)b * SEQ * DIM;
  const bf16* vbase = Vt + (size_t)b * DIM * SEQ;

  // staging geometry (per thread), both fully coalesced:
  // K: 32 rows x 384c: thread -> (row = tid>>3, 48-elem seg = (tid&7)*48), 6 x i4
  // V: 384 d-rows x 32m: thread -> (d = tid>>2 (+p*64), 8-elem seg = (tid&3)*8), 6 x i4
  int krow = tid >> 3, kcs = (tid & 7) * 48;
  int vd = tid >> 2, vmq = (tid & 3) * 8;

  // prologue: stage m-tile 0 directly
  {
    #pragma unroll
    for (int p = 0; p < 6; ++p)
      *(i4*)(&Kl[krow][kcs + p * 8]) =
          *(const i4*)(kbase + (size_t)krow * DIM + kcs + p * 8);
    #pragma unroll
    for (int p = 0; p < 6; ++p)
      *(i4*)(&Vl[vd + p * 64][vmq]) =
          *(const i4*)(vbase + (size_t)(vd + p * 64) * SEQ + vmq);
  }
  __syncthreads();

  for (int im = 0; im < SEQ / 32; ++im) {
    // S = Q * K^T : wave's 16 rows x 32 cols
    fx4 sa[2] = {zero, zero};
    #pragma unroll
    for (int ks = 0; ks < 12; ++ks) {
      #pragma unroll
      for (int ct = 0; ct < 2; ++ct) {
        short8 bfr = *(const short8*)(&Kl[ct * 16 + r][ks * 32 + kq * 8]);
        sa[ct] = MFMA(qf[ks], bfr, sa[ct]);
      }
    }
    // exp (no max subtraction), partial per-lane rowsum, P -> LDS
    #pragma unroll
    for (int rr = 0; rr < 4; ++rr) {
      float e0 = exp2f(sa[0][rr] * cexp);
      float e1 = exp2f(sa[1][rr] * cexp);
      int row = kq * 4 + rr;
      Pl[wave][row][r]      = __float2bfloat16(e0);
      Pl[wave][row][16 + r] = __float2bfloat16(e1);
      rs[rr] += e0 + e1;
    }
    __syncthreads();   // bB: Pl ready; all waves done reading Kl

    // issue next tile's global loads into registers (latency hides under PV)
    i4 kst[6], vst[6];
    int mn = (im + 1) * 32;
    bool more = (im + 1 < SEQ / 32);
    if (more) {
      #pragma unroll
      for (int p = 0; p < 6; ++p)
        kst[p] = *(const i4*)(kbase + (size_t)(mn + krow) * DIM + kcs + p * 8);
      #pragma unroll
      for (int p = 0; p < 6; ++p)
        vst[p] = *(const i4*)(vbase + (size_t)(vd + p * 64) * SEQ + mn + vmq);
    }

    // PV: O[rg*16+i][d] += P[rg*16+i][m] * V[m][d], wave's 96 d-cols
    short8 pa[4];
    #pragma unroll
    for (int rg = 0; rg < 4; ++rg)
      pa[rg] = *(const short8*)(&Pl[rg][r][kq * 8]);
    #pragma unroll
    for (int dtl = 0; dtl < 6; ++dtl) {
      short8 vfr = *(const short8*)(&Vl[(wave * 6 + dtl) * 16 + r][kq * 8]);
      #pragma unroll
      for (int rg = 0; rg < 4; ++rg)
        acc[rg][dtl] = MFMA(pa[rg], vfr, acc[rg][dtl]);
    }
    __syncthreads();   // bA: all waves done PV -> Vl and Pl free

    if (more) {
      #pragma unroll
      for (int p = 0; p < 6; ++p) *(i4*)(&Kl[krow][kcs + p * 8]) = kst[p];
      #pragma unroll
      for (int p = 0; p < 6; ++p) *(i4*)(&Vl[vd + p * 64][vmq]) = vst[p];
    }
    __syncthreads();   // bC: next K/V tiles ready
  }

  // final rowsum reduce over the 16 r-lanes (cols partition), share across waves
  #pragma unroll
  for (int rr = 0; rr < 4; ++rr) {
    float v = rs[rr];
    v += __shfl_xor(v, 1);
    v += __shfl_xor(v, 2);
    v += __shfl_xor(v, 4);
    v += __shfl_xor(v, 8);
    if (r == 0) rsum[wave * 16 + kq * 4 + rr] = v;
  }
  __syncthreads();
  // epilogue: divide and store transposed: out[b][d][n]
  float* ob = out + (size_t)b * DIM * SEQ;
  #pragma unroll
  for (int rg = 0; rg < 4; ++rg) {
    #pragma unroll
    for (int rr = 0; rr < 4; ++rr) {
      float inv = 1.0f / rsum[rg * 16 + kq * 4 + rr];
      int n = n0 + rg * 16 + kq * 4 + rr;
      #pragma unroll
      for (int dtl = 0; dtl < 6; ++dtl) {
        int d = (wave * 6 + dtl) * 16 + r;
        ob[(size_t)d * SEQ + n] = acc[rg][dtl][rr] * inv;
      }
    }
  }
}

extern "C" void kernel_launch(void* const* d_in, const int* in_sizes, int n_in,
                              void* d_out, int out_size, void* d_ws, size_t ws_size,
                              hipStream_t stream) {
  const float* x  = (const float*)d_in[0];
  const float* w1 = (const float*)d_in[1];
  const float* w2 = (const float*)d_in[2];
  float* out = (float*)d_out;

  char* ws = (char*)d_ws;
  size_t SZ = (size_t)NBATCH * SEQ * DIM * sizeof(bf16);   // 19,267,584 B
  bf16* Kb  = (bf16*)(ws);                 // [B][N][C]
  bf16* Qb  = (bf16*)(ws + SZ);            // [B][N][C]
  bf16* Vt  = (bf16*)(ws + 2 * SZ);        // [B][C][N]
  bf16* w1b = (bf16*)(ws + 3 * SZ);
  bf16* w2b = (bf16*)(ws + 3 * SZ + (size_t)DIM * DIM * sizeof(bf16));

  // 1) transpose+convert x -> Kb
  ktrans<<<dim3(SEQ / 64, DIM / 64, NBATCH), 256, 0, stream>>>(x, Kb);
  // 2) weights -> bf16
  kwconv<<<dim3(DIM * DIM / 256), 256, 0, stream>>>(w1, w2, w1b, w2b);
  // 3) Q[b][n][d] = sum_c Kb[b][n][c] * w1[d][c]
  kgemm<<<dim3(SEQ / 64, DIM / 64, NBATCH), 256, 0, stream>>>(
      Kb, (long long)SEQ * DIM, w1b, 0LL, Qb, (long long)SEQ * DIM, DIM);
  // 4) Vt[b][d][m] = sum_c w2[d][c] * Kb[b][m][c]
  kgemm<<<dim3(DIM / 64, SEQ / 64, NBATCH), 256, 0, stream>>>(
      w2b, 0LL, Kb, (long long)SEQ * DIM, Vt, (long long)DIM * SEQ, SEQ);
  // 5) fused attention -> out[b][d][n]  (batch on blockIdx.x -> one XCD per batch)
  kattn<<<dim3(NBATCH, SEQ / 64), 256, 0, stream>>>(Qb, Kb, Vt, out);
}